// Round 16
// baseline (240.550 us; speedup 1.0000x reference)
//
#include <hip/hip_runtime.h>
#include <stdint.h>

// Problem constants (B=4, C=256, C8=32, H=W=64, N=4096)
#define NB 4
#define NC 256
#define NN 4096

typedef __attribute__((ext_vector_type(8))) short bf16x8;
typedef __attribute__((ext_vector_type(4))) float f32x4;
typedef __attribute__((ext_vector_type(16))) float f32x16;
typedef __attribute__((ext_vector_type(8))) unsigned short u16x8;
typedef __attribute__((ext_vector_type(4))) unsigned short u16x4;
typedef __attribute__((ext_vector_type(4))) unsigned int u32x4;

#define MFMA32(a, b, c) __builtin_amdgcn_mfma_f32_32x32x16_bf16((a), (b), (c), 0, 0, 0)
#define LOG2E 1.4426950408889634f

__device__ __forceinline__ unsigned short bf16_rne(float f) {
    unsigned int u = __builtin_bit_cast(unsigned int, f);
    u += 0x7fffu + ((u >> 16) & 1u);
    return (unsigned short)(u >> 16);
}
__device__ __forceinline__ float bf16_to_f(unsigned short h) {
    return __builtin_bit_cast(float, (unsigned int)h << 16);
}
__device__ __forceinline__ float exp2_hw(float x) {
    float r;
    asm("v_exp_f32 %0, %1" : "=v"(r) : "v"(x));
    return r;
}
__device__ __forceinline__ unsigned int cvtpk_bf16(float lo, float hi) {
    unsigned int r;
    asm("v_cvt_pk_bf16_f32 %0, %1, %2" : "=v"(r) : "v"(lo), "v"(hi));
    return r;
}

// ---------------------------------------------------------------------------
// Projection kernel: q,k (fp32 -> bf16 hi/lo split) and v (bf16), BN folded;
// q scaled by log2(e). q/k layout: [B][N][32] bf16.
// v layout (PV-fragment order): [B][jg = N/8][c = 256][8 j] bf16.
// v-part thread mapping: thread (cg = t&63, pg = t>>6) owns channels cg*4..+3
// x 8 CONSECUTIVE positions pg*8..+7 -> each result is natively one u16x8 =
// one V'[jg][c][8] line, stored directly (no LDS transpose — R14's vt buffer
// was a structural 8-way bank conflict). x-reads become wave-broadcast (free).
// Grid: 512 blocks x 256 threads; block handles 32 spatial positions.
// ---------------------------------------------------------------------------
__global__ __launch_bounds__(256) void proj_kernel(
    const float* __restrict__ x,
    const float* __restrict__ wq,
    const float* __restrict__ qg, const float* __restrict__ qb,
    const float* __restrict__ qm, const float* __restrict__ qv,
    const float* __restrict__ wk,
    const float* __restrict__ kg, const float* __restrict__ kb,
    const float* __restrict__ km, const float* __restrict__ kv,
    const float* __restrict__ wv,
    const float* __restrict__ vg, const float* __restrict__ vb,
    const float* __restrict__ vm, const float* __restrict__ vv,
    unsigned short* __restrict__ qhi, unsigned short* __restrict__ qlo,
    unsigned short* __restrict__ khi, unsigned short* __restrict__ klo,
    unsigned short* __restrict__ vws)
{
    __shared__ float xt[NC * 36 + 8];
    const int t = threadIdx.x;
    const int blk = blockIdx.x;
    const int b = blk >> 7;
    const int n0 = (blk & 127) << 5;
    const float* xb = x + ((size_t)b << 20);

    for (int idx = t; idx < NC * 32; idx += 256) {
        int c = idx >> 5, j = idx & 31;
        xt[c * 36 + j] = xb[((size_t)c << 12) + n0 + j];
    }
    __syncthreads();

    // ---- q / k (unchanged): thread = (p = t&31, og = t>>5) ----
    {
        const int p = t & 31;
        const int og = t >> 5;
        const bool is_k = og >= 4;
        const int o0 = (og & 3) << 3;
        const float* w = is_k ? wk : wq;
        float acc[8];
#pragma unroll
        for (int o = 0; o < 8; ++o) acc[o] = 0.f;
        for (int c4 = 0; c4 < NC; c4 += 4) {
            float x0 = xt[(c4 + 0) * 36 + p];
            float x1 = xt[(c4 + 1) * 36 + p];
            float x2 = xt[(c4 + 2) * 36 + p];
            float x3 = xt[(c4 + 3) * 36 + p];
#pragma unroll
            for (int o = 0; o < 8; ++o) {
                const float4 w4 = *(const float4*)&w[(o0 + o) * NC + c4];
                acc[o] += w4.x * x0 + w4.y * x1 + w4.z * x2 + w4.w * x3;
            }
        }
        const float* G = is_k ? kg : qg;
        const float* Bb = is_k ? kb : qb;
        const float* M = is_k ? km : qm;
        const float* V = is_k ? kv : qv;
        u16x8 hv, lv;
#pragma unroll
        for (int o = 0; o < 8; ++o) {
            int oo = o0 + o;
            float sc = G[oo] / sqrtf(V[oo] + 1e-5f);
            float val = acc[o] * sc + (Bb[oo] - M[oo] * sc);
            if (!is_k) val *= LOG2E;
            unsigned short h = bf16_rne(val);
            hv[o] = h;
            lv[o] = bf16_rne(val - bf16_to_f(h));
        }
        size_t base = ((size_t)(b << 12) + n0 + p) * 32 + o0;
        *(u16x8*)&(is_k ? khi : qhi)[base] = hv;
        *(u16x8*)&(is_k ? klo : qlo)[base] = lv;
    }

    // ---- v : thread = (cg = t&63, pg = t>>6); 4 channels x 8 positions ----
    {
        const int cg = t & 63;
        const int pg = t >> 6;
        const int p0 = pg << 3;
        float acc[8][4];   // [pp][o]
#pragma unroll
        for (int pp = 0; pp < 8; ++pp)
#pragma unroll
            for (int o = 0; o < 4; ++o) acc[pp][o] = 0.f;
        for (int c4 = 0; c4 < NC; c4 += 4) {
            float4 w4[4];
#pragma unroll
            for (int o = 0; o < 4; ++o)
                w4[o] = *(const float4*)&wv[(cg * 4 + o) * NC + c4];
#pragma unroll
            for (int r = 0; r < 4; ++r) {
                const float4 xa = *(const float4*)&xt[(c4 + r) * 36 + p0];
                const float4 xc = *(const float4*)&xt[(c4 + r) * 36 + p0 + 4];
                const float xs[8] = {xa.x, xa.y, xa.z, xa.w, xc.x, xc.y, xc.z, xc.w};
#pragma unroll
                for (int o = 0; o < 4; ++o) {
                    const float wr = r == 0 ? w4[o].x : r == 1 ? w4[o].y
                                   : r == 2 ? w4[o].z : w4[o].w;
#pragma unroll
                    for (int pp = 0; pp < 8; ++pp) acc[pp][o] += wr * xs[pp];
                }
            }
        }
        const size_t vrow = (size_t)b * (NN / 8) + (n0 >> 3) + pg;
#pragma unroll
        for (int o = 0; o < 4; ++o) {
            const int c = cg * 4 + o;
            float sc = vg[c] / sqrtf(vv[c] + 1e-5f);
            float sh = vb[c] - vm[c] * sc;
            u16x8 st;
#pragma unroll
            for (int pp = 0; pp < 8; ++pp) st[pp] = bf16_rne(acc[pp][o] * sc + sh);
            *(u16x8*)&vws[(vrow * NC + c) * 8] = st;
        }
    }
}

// ---------------------------------------------------------------------------
// Flash attention v11: c-split grid — 1024 blocks x 256 threads. Block =
// 32 q-rows x 128 c (ch = channel half); 4 waves = 2 wc(64c) x 2 wjp.
// Grid cap now 4 blocks/CU (R14 was grid-limited to 2). QK dup 4x total
// (+43% MFMA, pipe only ~7% busy — absorbed). Main loop: zero LDS / zero
// barriers, K,V direct-from-global (L2-hot). Epilogue LDS 17.4KB.
// ---------------------------------------------------------------------------
__global__ __launch_bounds__(256, 2) void attn_kernel(
    const float* __restrict__ x, const float* __restrict__ gamma_p,
    const unsigned short* __restrict__ qhi, const unsigned short* __restrict__ qlo,
    const unsigned short* __restrict__ khi, const unsigned short* __restrict__ klo,
    const unsigned short* __restrict__ vws,
    float* __restrict__ out)
{
    __shared__ __align__(16) char smem[17408];
    const int t = threadIdx.x;
    const int pb = blockIdx.x;
    const int xcd = pb & 7;
    const int b = xcd >> 1;
    const int hi2 = pb >> 3;                  // [0,128)
    const int ch = hi2 & 1;                   // channel half
    const int tile = ((xcd & 1) << 6) + (hi2 >> 1);
    const int i0 = tile << 5;
    const int w = t >> 6, lane = t & 63;
    const int h = lane >> 5, il = lane & 31;
    const int wc = w & 1, wjp = w >> 1;

    const size_t bN32 = (size_t)b * (NN * 32);
    const unsigned short* kh_g = khi + bN32;
    const unsigned short* kl_g = klo + bN32;
    const unsigned short* v_g = vws + (size_t)b * (NC * NN);

    // Q B-frags: lane holds Q[i = i0+il][c = ks*16 + h*8 + e], hi/lo
    bf16x8 qh[2], ql[2];
    {
        size_t qoff = bN32 + (size_t)(i0 + il) * 32 + h * 8;
        qh[0] = *(const bf16x8*)&qhi[qoff];
        ql[0] = *(const bf16x8*)&qlo[qoff];
        qh[1] = *(const bf16x8*)&qhi[qoff + 16];
        ql[1] = *(const bf16x8*)&qlo[qoff + 16];
    }

    // K A-frag row: S^T row (wjp*32+il) <-> global row kmap(il) (swap bits 2<->3)
    size_t krow;
    {
        int u = il;
        int kmp = (u & 0x13) | ((u & 4) << 1) | ((u & 8) >> 1);
        krow = ((size_t)(wjp * 32 + kmp) * 32) + h * 8;   // + j0*32 per jt
    }

    f32x16 acc[2];
#pragma unroll
    for (int fc = 0; fc < 2; ++fc)
#pragma unroll
        for (int e = 0; e < 16; ++e) acc[fc][e] = 0.f;
    float m_run = -3.0e38f, l_part = 0.f;   // per lane: q-row i = il

    auto kfetch = [&](int jt, bf16x8* kr) {
        const size_t rb = krow + (size_t)(jt << 6) * 32;
        kr[0] = *(const bf16x8*)&kh_g[rb];
        kr[1] = *(const bf16x8*)&kh_g[rb + 16];
        kr[2] = *(const bf16x8*)&kl_g[rb];
        kr[3] = *(const bf16x8*)&kl_g[rb + 16];
    };
    auto vfetch = [&](int jt, bf16x8* vr) {
#pragma unroll
        for (int fc = 0; fc < 2; ++fc)
#pragma unroll
            for (int ks = 0; ks < 2; ++ks) {
                const int c = ch * 128 + wc * 64 + fc * 32 + il;
                const size_t jg = (size_t)(jt * 8 + wjp * 4 + ks * 2 + h);
                vr[fc * 2 + ks] = *(const bf16x8*)&v_g[(jg * NC + c) * 8];
            }
    };

    bf16x8 kreg[2][4];
    kfetch(0, kreg[0]);

#pragma unroll 2
    for (int jt = 0; jt < NN / 64; ++jt) {
        const int cb = jt & 1;
        bf16x8 vreg[4];
        vfetch(jt, vreg);                        // lands under QK + softmax
        if (jt < NN / 64 - 1) kfetch(jt + 1, kreg[cb ^ 1]);

        // ---- S^T = K·Q (32x32, hi/lo, log2 domain): D[j-row][i = il] ----
        f32x16 s2;
#pragma unroll
        for (int e = 0; e < 16; ++e) s2[e] = 0.f;
        __builtin_amdgcn_s_setprio(1);
#pragma unroll
        for (int ks = 0; ks < 2; ++ks) {
            s2 = MFMA32(kreg[cb][2 + ks], qh[ks], s2);
            s2 = MFMA32(kreg[cb][ks], ql[ks], s2);
            s2 = MFMA32(kreg[cb][ks], qh[ks], s2);
        }
        __builtin_amdgcn_s_setprio(0);

        // ---- online softmax (row i = il; halves combined via xor-32) ----
        float tl = s2[0];
#pragma unroll
        for (int e = 1; e < 16; ++e) tl = fmaxf(tl, s2[e]);
        tl = fmaxf(tl, __shfl_xor(tl, 32));

        if (!__all(tl <= m_run + 11.0f)) {
            float nm = fmaxf(m_run, tl);
            float rs = exp2_hw(m_run - nm);
            m_run = nm;
            l_part *= rs;
#pragma unroll
            for (int fc = 0; fc < 2; ++fc)
#pragma unroll
                for (int e = 0; e < 16; ++e) acc[fc][e] *= rs;
        }

        float p[16];
#pragma unroll
        for (int e = 0; e < 16; ++e) p[e] = exp2_hw(s2[e] - m_run);
        float ls = 0.f;
#pragma unroll
        for (int e = 0; e < 16; ++e) ls += p[e];
        ls += __shfl_xor(ls, 32);
        l_part += ls;

        // ---- P -> bf16 B-frags (j-order correct via kmap) ----
        bf16x8 pa[2];
#pragma unroll
        for (int ks = 0; ks < 2; ++ks) {
            u32x4 pw;
            pw[0] = cvtpk_bf16(p[ks * 8 + 0], p[ks * 8 + 1]);
            pw[1] = cvtpk_bf16(p[ks * 8 + 2], p[ks * 8 + 3]);
            pw[2] = cvtpk_bf16(p[ks * 8 + 4], p[ks * 8 + 5]);
            pw[3] = cvtpk_bf16(p[ks * 8 + 6], p[ks * 8 + 7]);
            pa[ks] = __builtin_bit_cast(bf16x8, pw);
        }

        // ---- PV: acc[fc] = V[c][j] (A) x P[j][i] (B), D[c-row][i-col] ----
        __builtin_amdgcn_s_setprio(1);
#pragma unroll
        for (int fc = 0; fc < 2; ++fc) {
#pragma unroll
            for (int ks = 0; ks < 2; ++ks)
                acc[fc] = MFMA32(vreg[fc * 2 + ks], pa[ks], acc[fc]);
        }
        __builtin_amdgcn_s_setprio(0);
    }

    // ---- merge wjp partials (in-place buffer), normalize, residual, store ----
    float* ml = (float*)(smem + 16384);       // m: [w*32+i], l: [128 + w*32+i]
    if (lane < 32) {
        ml[w * 32 + il] = m_run;
        ml[128 + w * 32 + il] = l_part;
    }
    __syncthreads();

    const int wp = w ^ 2;                     // partner wave (wjp flipped)
    float m_o = ml[wp * 32 + il];
    float l_o = ml[128 + wp * 32 + il];
    float m_g = fmaxf(m_run, m_o);
    float a_s = exp2_hw(m_run - m_g);
    float l_tot = l_part * a_s + l_o * exp2_hw(m_o - m_g);
#pragma unroll
    for (int fc = 0; fc < 2; ++fc)
#pragma unroll
        for (int e = 0; e < 16; ++e) acc[fc][e] *= a_s;

    float* AB = (float*)smem;                 // [128 c-local][32 i], in-place
    if (wjp == 1) {
#pragma unroll
        for (int fc = 0; fc < 2; ++fc)
#pragma unroll
            for (int e = 0; e < 16; ++e) {
                int cl = wc * 64 + fc * 32 + (e & 3) + 8 * (e >> 2) + 4 * h;
                AB[cl * 32 + il] = acc[fc][e];
            }
    }
    __syncthreads();

    if (wjp == 0) {
        const float gm = gamma_p[0];
        const float linv = gm / l_tot;
#pragma unroll
        for (int fc = 0; fc < 2; ++fc)
#pragma unroll
            for (int e = 0; e < 16; ++e) {
                int cl = wc * 64 + fc * 32 + (e & 3) + 8 * (e >> 2) + 4 * h;
                AB[cl * 32 + il] = (acc[fc][e] + AB[cl * 32 + il]) * linv;
            }
    }
    __syncthreads();

    const float* xb = x + ((size_t)b << 20);
    float* ob = out + ((size_t)b << 20);
#pragma unroll
    for (int it = 0; it < 4; ++it) {
        int cl = (t >> 3) + (it << 5);
        int c = ch * 128 + cl;
        int j = t & 7;
        f32x4 v = *(const f32x4*)&AB[cl * 32 + j * 4];
        f32x4 xv = *(const f32x4*)&xb[((size_t)c << 12) + i0 + j * 4];
        v += xv;
        *(f32x4*)&ob[((size_t)c << 12) + i0 + j * 4] = v;
    }
}

// ---------------------------------------------------------------------------
extern "C" void kernel_launch(void* const* d_in, const int* in_sizes, int n_in,
                              void* d_out, int out_size, void* d_ws, size_t ws_size,
                              hipStream_t stream)
{
    (void)in_sizes; (void)n_in; (void)out_size; (void)ws_size;
    const float* x = (const float*)d_in[0];
    const float* wq = (const float*)d_in[1];
    const float* qg = (const float*)d_in[2];
    const float* qb = (const float*)d_in[3];
    const float* qm = (const float*)d_in[4];
    const float* qv = (const float*)d_in[5];
    const float* wk = (const float*)d_in[6];
    const float* kg = (const float*)d_in[7];
    const float* kb = (const float*)d_in[8];
    const float* km = (const float*)d_in[9];
    const float* kv = (const float*)d_in[10];
    const float* wv = (const float*)d_in[11];
    const float* vg = (const float*)d_in[12];
    const float* vb = (const float*)d_in[13];
    const float* vm = (const float*)d_in[14];
    const float* vv = (const float*)d_in[15];
    const float* gamma = (const float*)d_in[16];

    unsigned short* ws = (unsigned short*)d_ws;
    const size_t QK = (size_t)NB * NN * 32;
    unsigned short* qhi = ws;
    unsigned short* qlo = ws + QK;
    unsigned short* khi = ws + 2 * QK;
    unsigned short* klo = ws + 3 * QK;
    unsigned short* vws = ws + 4 * QK;

    proj_kernel<<<dim3(512), dim3(256), 0, stream>>>(
        x, wq, qg, qb, qm, qv, wk, kg, kb, km, kv, wv, vg, vb, vm, vv,
        qhi, qlo, khi, klo, vws);
    attn_kernel<<<dim3(1024), dim3(256), 0, stream>>>(
        x, gamma, qhi, qlo, khi, klo, vws, (float*)d_out);
}

// Round 17
// 154.413 us; speedup vs baseline: 1.5578x; 1.5578x over previous
//
#include <hip/hip_runtime.h>
#include <stdint.h>

// Problem constants (B=4, C=256, C8=32, H=W=64, N=4096)
#define NB 4
#define NC 256
#define NN 4096

typedef __attribute__((ext_vector_type(8))) short bf16x8;
typedef __attribute__((ext_vector_type(4))) float f32x4;
typedef __attribute__((ext_vector_type(16))) float f32x16;
typedef __attribute__((ext_vector_type(8))) unsigned short u16x8;
typedef __attribute__((ext_vector_type(4))) unsigned short u16x4;
typedef __attribute__((ext_vector_type(4))) unsigned int u32x4;

#define MFMA32(a, b, c) __builtin_amdgcn_mfma_f32_32x32x16_bf16((a), (b), (c), 0, 0, 0)
#define LOG2E 1.4426950408889634f

__device__ __forceinline__ unsigned short bf16_rne(float f) {
    unsigned int u = __builtin_bit_cast(unsigned int, f);
    u += 0x7fffu + ((u >> 16) & 1u);
    return (unsigned short)(u >> 16);
}
__device__ __forceinline__ float bf16_to_f(unsigned short h) {
    return __builtin_bit_cast(float, (unsigned int)h << 16);
}
__device__ __forceinline__ float exp2_hw(float x) {
    float r;
    asm("v_exp_f32 %0, %1" : "=v"(r) : "v"(x));
    return r;
}
__device__ __forceinline__ unsigned int cvtpk_bf16(float lo, float hi) {
    unsigned int r;
    asm("v_cvt_pk_bf16_f32 %0, %1, %2" : "=v"(r) : "v"(lo), "v"(hi));
    return r;
}

// ---------------------------------------------------------------------------
// convert_v: one-time transpose of wv into wvT[c_in][c_out] with BN scale
// folded. 256x256 floats = 256KB. Writes coalesced (o lane-consecutive);
// reads strided but one-time/L2-absorbed. Grid 256 x 256.
// ---------------------------------------------------------------------------
__global__ __launch_bounds__(256) void convert_v(
    const float* __restrict__ wv, const float* __restrict__ vg,
    const float* __restrict__ vv, float* __restrict__ wvt)
{
    const int idx = blockIdx.x * 256 + threadIdx.x;
    const int ci = idx >> 8, o = idx & 255;
    const float sc = vg[o] / sqrtf(vv[o] + 1e-5f);
    wvt[ci * NC + o] = wv[o * NC + ci] * sc;
}

// ---------------------------------------------------------------------------
// Projection kernel: q,k (fp32 -> bf16 hi/lo split, R2 mapping) and v via
// TRANSPOSED weights. q/k layout: [B][N][32] bf16.
// v layout (PV-fragment order): [B][jg = N/8][c = 256][8 j] bf16.
// v-part: thread (cg = t&63, pg = t>>6) owns channels {cg+64*o} x 8
// consecutive positions pg*8..+7. Weight reads wvT[ci][cg+64o] are
// lane-consecutive (coalesced); x reads wave-broadcast from LDS; each store
// is a u16x8 V' line, 64 lanes contiguous = 1KB per instruction. Zero LDS
// transpose (R14's vt was bank-conflicted; R16's weights were uncoalesced).
// Grid: 512 blocks x 256 threads; block handles 32 spatial positions.
// ---------------------------------------------------------------------------
__global__ __launch_bounds__(256) void proj_kernel(
    const float* __restrict__ x,
    const float* __restrict__ wq,
    const float* __restrict__ qg, const float* __restrict__ qb,
    const float* __restrict__ qm, const float* __restrict__ qv,
    const float* __restrict__ wk,
    const float* __restrict__ kg, const float* __restrict__ kb,
    const float* __restrict__ km, const float* __restrict__ kv,
    const float* __restrict__ wvt,
    const float* __restrict__ vg, const float* __restrict__ vb,
    const float* __restrict__ vm, const float* __restrict__ vv,
    unsigned short* __restrict__ qhi, unsigned short* __restrict__ qlo,
    unsigned short* __restrict__ khi, unsigned short* __restrict__ klo,
    unsigned short* __restrict__ vws)
{
    __shared__ float xt[NC * 36 + 8];
    const int t = threadIdx.x;
    const int blk = blockIdx.x;
    const int b = blk >> 7;
    const int n0 = (blk & 127) << 5;
    const float* xb = x + ((size_t)b << 20);

    for (int idx = t; idx < NC * 32; idx += 256) {
        int c = idx >> 5, j = idx & 31;
        xt[c * 36 + j] = xb[((size_t)c << 12) + n0 + j];
    }
    __syncthreads();

    // ---- q / k (R2 mapping): thread = (p = t&31, og = t>>5) ----
    {
        const int p = t & 31;
        const int og = t >> 5;
        const bool is_k = og >= 4;
        const int o0 = (og & 3) << 3;
        const float* w = is_k ? wk : wq;
        float acc[8];
#pragma unroll
        for (int o = 0; o < 8; ++o) acc[o] = 0.f;
        for (int c4 = 0; c4 < NC; c4 += 4) {
            float x0 = xt[(c4 + 0) * 36 + p];
            float x1 = xt[(c4 + 1) * 36 + p];
            float x2 = xt[(c4 + 2) * 36 + p];
            float x3 = xt[(c4 + 3) * 36 + p];
#pragma unroll
            for (int o = 0; o < 8; ++o) {
                const float4 w4 = *(const float4*)&w[(o0 + o) * NC + c4];
                acc[o] += w4.x * x0 + w4.y * x1 + w4.z * x2 + w4.w * x3;
            }
        }
        const float* G = is_k ? kg : qg;
        const float* Bb = is_k ? kb : qb;
        const float* M = is_k ? km : qm;
        const float* V = is_k ? kv : qv;
        u16x8 hv, lv;
#pragma unroll
        for (int o = 0; o < 8; ++o) {
            int oo = o0 + o;
            float sc = G[oo] / sqrtf(V[oo] + 1e-5f);
            float val = acc[o] * sc + (Bb[oo] - M[oo] * sc);
            if (!is_k) val *= LOG2E;
            unsigned short h = bf16_rne(val);
            hv[o] = h;
            lv[o] = bf16_rne(val - bf16_to_f(h));
        }
        size_t base = ((size_t)(b << 12) + n0 + p) * 32 + o0;
        *(u16x8*)&(is_k ? khi : qhi)[base] = hv;
        *(u16x8*)&(is_k ? klo : qlo)[base] = lv;
    }

    // ---- v : thread = (cg = t&63, pg = t>>6); channels {cg+64o} x 8 pos ----
    {
        const int cg = t & 63;
        const int pg = t >> 6;
        const int p0 = pg << 3;
        float acc[8][4];   // [pp][o], channel c = cg + 64*o
#pragma unroll
        for (int pp = 0; pp < 8; ++pp)
#pragma unroll
            for (int o = 0; o < 4; ++o) acc[pp][o] = 0.f;
        for (int c4 = 0; c4 < NC; c4 += 4) {
#pragma unroll
            for (int r = 0; r < 4; ++r) {
                const int ci = c4 + r;
                const float w0 = wvt[ci * NC + cg];
                const float w1 = wvt[ci * NC + cg + 64];
                const float w2 = wvt[ci * NC + cg + 128];
                const float w3 = wvt[ci * NC + cg + 192];
                const float4 xa = *(const float4*)&xt[ci * 36 + p0];
                const float4 xc = *(const float4*)&xt[ci * 36 + p0 + 4];
                const float xs[8] = {xa.x, xa.y, xa.z, xa.w,
                                     xc.x, xc.y, xc.z, xc.w};
#pragma unroll
                for (int pp = 0; pp < 8; ++pp) {
                    acc[pp][0] += w0 * xs[pp];
                    acc[pp][1] += w1 * xs[pp];
                    acc[pp][2] += w2 * xs[pp];
                    acc[pp][3] += w3 * xs[pp];
                }
            }
        }
        const size_t vrow = (size_t)b * (NN / 8) + (n0 >> 3) + pg;
#pragma unroll
        for (int o = 0; o < 4; ++o) {
            const int c = cg + (o << 6);
            const float sc = vg[c] / sqrtf(vv[c] + 1e-5f);
            const float sh = vb[c] - vm[c] * sc;   // scale already in wvt
            u16x8 st;
#pragma unroll
            for (int pp = 0; pp < 8; ++pp) st[pp] = bf16_rne(acc[pp][o] + sh);
            *(u16x8*)&vws[(vrow * NC + c) * 8] = st;
        }
    }
}

// ---------------------------------------------------------------------------
// Flash attention (R14 verbatim — measured 85 us): 512 blocks x 256 threads,
// 4 waves = 2 wc x 2 wjp, 32x32x16. Main loop: zero LDS / zero barriers,
// K,V direct-from-global (L2-hot). Epilogue merged in-place (33.8KB LDS).
// R16's c-split regressed (+19 us): 2x K L2 traffic + QK duplication.
// ---------------------------------------------------------------------------
__global__ __launch_bounds__(256, 2) void attn_kernel(
    const float* __restrict__ x, const float* __restrict__ gamma_p,
    const unsigned short* __restrict__ qhi, const unsigned short* __restrict__ qlo,
    const unsigned short* __restrict__ khi, const unsigned short* __restrict__ klo,
    const unsigned short* __restrict__ vws,
    float* __restrict__ out)
{
    __shared__ __align__(16) char smem[33792];
    const int t = threadIdx.x;
    const int pb = blockIdx.x;
    const int xcd = pb & 7;
    const int b = xcd >> 1;
    const int tile = ((xcd & 1) << 6) + (pb >> 3);
    const int i0 = tile << 5;
    const int w = t >> 6, lane = t & 63;
    const int h = lane >> 5, il = lane & 31;
    const int wc = w & 1, wjp = w >> 1;

    const size_t bN32 = (size_t)b * (NN * 32);
    const unsigned short* kh_g = khi + bN32;
    const unsigned short* kl_g = klo + bN32;
    const unsigned short* v_g = vws + (size_t)b * (NC * NN);

    // Q B-frags: lane holds Q[i = i0+il][c = ks*16 + h*8 + e], hi/lo
    bf16x8 qh[2], ql[2];
    {
        size_t qoff = bN32 + (size_t)(i0 + il) * 32 + h * 8;
        qh[0] = *(const bf16x8*)&qhi[qoff];
        ql[0] = *(const bf16x8*)&qlo[qoff];
        qh[1] = *(const bf16x8*)&qhi[qoff + 16];
        ql[1] = *(const bf16x8*)&qlo[qoff + 16];
    }

    // K A-frag row: S^T row (wjp*32+il) <-> global row kmap(il) (swap bits 2<->3)
    size_t krow;
    {
        int u = il;
        int kmp = (u & 0x13) | ((u & 4) << 1) | ((u & 8) >> 1);
        krow = ((size_t)(wjp * 32 + kmp) * 32) + h * 8;   // + j0*32 per jt
    }

    f32x16 acc[4];
#pragma unroll
    for (int fc = 0; fc < 4; ++fc)
#pragma unroll
        for (int e = 0; e < 16; ++e) acc[fc][e] = 0.f;
    float m_run = -3.0e38f, l_part = 0.f;   // per lane: q-row i = il

    auto kfetch = [&](int jt, bf16x8* kr) {
        const size_t rb = krow + (size_t)(jt << 6) * 32;
        kr[0] = *(const bf16x8*)&kh_g[rb];
        kr[1] = *(const bf16x8*)&kh_g[rb + 16];
        kr[2] = *(const bf16x8*)&kl_g[rb];
        kr[3] = *(const bf16x8*)&kl_g[rb + 16];
    };
    auto vfetch = [&](int jt, bf16x8* vr) {
#pragma unroll
        for (int fc = 0; fc < 4; ++fc)
#pragma unroll
            for (int ks = 0; ks < 2; ++ks) {
                const int c = wc * 128 + fc * 32 + il;
                const size_t jg = (size_t)(jt * 8 + wjp * 4 + ks * 2 + h);
                vr[fc * 2 + ks] = *(const bf16x8*)&v_g[(jg * NC + c) * 8];
            }
    };

    bf16x8 kreg[2][4];
    kfetch(0, kreg[0]);

#pragma unroll 2
    for (int jt = 0; jt < NN / 64; ++jt) {
        const int cb = jt & 1;
        bf16x8 vreg[8];
        vfetch(jt, vreg);                        // lands under QK + softmax
        if (jt < NN / 64 - 1) kfetch(jt + 1, kreg[cb ^ 1]);

        // ---- S^T = K·Q (32x32, hi/lo, log2 domain): D[j-row][i = il] ----
        f32x16 s2;
#pragma unroll
        for (int e = 0; e < 16; ++e) s2[e] = 0.f;
        __builtin_amdgcn_s_setprio(1);
#pragma unroll
        for (int ks = 0; ks < 2; ++ks) {
            s2 = MFMA32(kreg[cb][2 + ks], qh[ks], s2);
            s2 = MFMA32(kreg[cb][ks], ql[ks], s2);
            s2 = MFMA32(kreg[cb][ks], qh[ks], s2);
        }
        __builtin_amdgcn_s_setprio(0);

        // ---- online softmax (row i = il; halves combined via xor-32) ----
        float tl = s2[0];
#pragma unroll
        for (int e = 1; e < 16; ++e) tl = fmaxf(tl, s2[e]);
        tl = fmaxf(tl, __shfl_xor(tl, 32));

        if (!__all(tl <= m_run + 11.0f)) {
            float nm = fmaxf(m_run, tl);
            float rs = exp2_hw(m_run - nm);
            m_run = nm;
            l_part *= rs;
#pragma unroll
            for (int fc = 0; fc < 4; ++fc)
#pragma unroll
                for (int e = 0; e < 16; ++e) acc[fc][e] *= rs;
        }

        float p[16];
#pragma unroll
        for (int e = 0; e < 16; ++e) p[e] = exp2_hw(s2[e] - m_run);
        float ls = 0.f;
#pragma unroll
        for (int e = 0; e < 16; ++e) ls += p[e];
        ls += __shfl_xor(ls, 32);
        l_part += ls;

        // ---- P -> bf16 B-frags (j-order correct via kmap) ----
        bf16x8 pa[2];
#pragma unroll
        for (int ks = 0; ks < 2; ++ks) {
            u32x4 pw;
            pw[0] = cvtpk_bf16(p[ks * 8 + 0], p[ks * 8 + 1]);
            pw[1] = cvtpk_bf16(p[ks * 8 + 2], p[ks * 8 + 3]);
            pw[2] = cvtpk_bf16(p[ks * 8 + 4], p[ks * 8 + 5]);
            pw[3] = cvtpk_bf16(p[ks * 8 + 6], p[ks * 8 + 7]);
            pa[ks] = __builtin_bit_cast(bf16x8, pw);
        }

        // ---- PV: acc[fc] = V[c][j] (A) x P[j][i] (B), D[c-row][i-col] ----
        __builtin_amdgcn_s_setprio(1);
#pragma unroll
        for (int fc = 0; fc < 4; ++fc) {
#pragma unroll
            for (int ks = 0; ks < 2; ++ks)
                acc[fc] = MFMA32(vreg[fc * 2 + ks], pa[ks], acc[fc]);
        }
        __builtin_amdgcn_s_setprio(0);
    }

    // ---- merge wjp partials (in-place buffer), normalize, residual, store ----
    float* ml = (float*)(smem + 32768);       // m: [w*32+i], l: [128 + w*32+i]
    if (lane < 32) {
        ml[w * 32 + il] = m_run;
        ml[128 + w * 32 + il] = l_part;
    }
    __syncthreads();

    const int wp = w ^ 2;                     // partner wave (wjp flipped)
    float m_o = ml[wp * 32 + il];
    float l_o = ml[128 + wp * 32 + il];
    float m_g = fmaxf(m_run, m_o);
    float a_s = exp2_hw(m_run - m_g);
    float l_tot = l_part * a_s + l_o * exp2_hw(m_o - m_g);
#pragma unroll
    for (int fc = 0; fc < 4; ++fc)
#pragma unroll
        for (int e = 0; e < 16; ++e) acc[fc][e] *= a_s;

    float* AB = (float*)smem;                 // [256 c][32 i], in-place
    if (wjp == 1) {
#pragma unroll
        for (int fc = 0; fc < 4; ++fc)
#pragma unroll
            for (int e = 0; e < 16; ++e) {
                int c = wc * 128 + fc * 32 + (e & 3) + 8 * (e >> 2) + 4 * h;
                AB[c * 32 + il] = acc[fc][e];
            }
    }
    __syncthreads();

    if (wjp == 0) {
        const float gm = gamma_p[0];
        const float linv = gm / l_tot;
#pragma unroll
        for (int fc = 0; fc < 4; ++fc)
#pragma unroll
            for (int e = 0; e < 16; ++e) {
                int c = wc * 128 + fc * 32 + (e & 3) + 8 * (e >> 2) + 4 * h;
                AB[c * 32 + il] = (acc[fc][e] + AB[c * 32 + il]) * linv;
            }
    }
    __syncthreads();

    const float* xb = x + ((size_t)b << 20);
    float* ob = out + ((size_t)b << 20);
#pragma unroll
    for (int it = 0; it < 8; ++it) {
        int c = (t >> 3) + (it << 5);
        int j = t & 7;
        f32x4 v = *(const f32x4*)&AB[c * 32 + j * 4];
        f32x4 xv = *(const f32x4*)&xb[((size_t)c << 12) + i0 + j * 4];
        v += xv;
        *(f32x4*)&ob[((size_t)c << 12) + i0 + j * 4] = v;
    }
}

// ---------------------------------------------------------------------------
extern "C" void kernel_launch(void* const* d_in, const int* in_sizes, int n_in,
                              void* d_out, int out_size, void* d_ws, size_t ws_size,
                              hipStream_t stream)
{
    (void)in_sizes; (void)n_in; (void)out_size; (void)ws_size;
    const float* x = (const float*)d_in[0];
    const float* wq = (const float*)d_in[1];
    const float* qg = (const float*)d_in[2];
    const float* qb = (const float*)d_in[3];
    const float* qm = (const float*)d_in[4];
    const float* qv = (const float*)d_in[5];
    const float* wk = (const float*)d_in[6];
    const float* kg = (const float*)d_in[7];
    const float* kb = (const float*)d_in[8];
    const float* km = (const float*)d_in[9];
    const float* kv = (const float*)d_in[10];
    const float* wv = (const float*)d_in[11];
    const float* vg = (const float*)d_in[12];
    const float* vb = (const float*)d_in[13];
    const float* vm = (const float*)d_in[14];
    const float* vv = (const float*)d_in[15];
    const float* gamma = (const float*)d_in[16];

    unsigned short* ws = (unsigned short*)d_ws;
    const size_t QK = (size_t)NB * NN * 32;       // 524288 ushorts
    const size_t VSZ = (size_t)NB * NC * NN;      // 4194304 ushorts
    unsigned short* qhi = ws;
    unsigned short* qlo = ws + QK;
    unsigned short* khi = ws + 2 * QK;
    unsigned short* klo = ws + 3 * QK;
    unsigned short* vws = ws + 4 * QK;
    float* wvt = (float*)(ws + 4 * QK + VSZ);     // 65536 floats (256KB)

    convert_v<<<dim3(256), dim3(256), 0, stream>>>(wv, vg, vv, wvt);
    proj_kernel<<<dim3(512), dim3(256), 0, stream>>>(
        x, wq, qg, qb, qm, qv, wk, kg, kb, km, kv, wvt, vg, vb, vm, vv,
        qhi, qlo, khi, klo, vws);
    attn_kernel<<<dim3(512), dim3(256), 0, stream>>>(
        x, gamma, qhi, qlo, khi, klo, vws, (float*)d_out);
}

// Round 20
// 153.270 us; speedup vs baseline: 1.5695x; 1.0075x over previous
//
#include <hip/hip_runtime.h>
#include <stdint.h>

// Problem constants (B=4, C=256, C8=32, H=W=64, N=4096)
#define NB 4
#define NC 256
#define NN 4096

typedef __attribute__((ext_vector_type(8))) short bf16x8;
typedef __attribute__((ext_vector_type(4))) float f32x4;
typedef __attribute__((ext_vector_type(16))) float f32x16;
typedef __attribute__((ext_vector_type(8))) unsigned short u16x8;
typedef __attribute__((ext_vector_type(4))) unsigned short u16x4;
typedef __attribute__((ext_vector_type(4))) unsigned int u32x4;

#define MFMA32(a, b, c) __builtin_amdgcn_mfma_f32_32x32x16_bf16((a), (b), (c), 0, 0, 0)
#define LOG2E 1.4426950408889634f

__device__ __forceinline__ unsigned short bf16_rne(float f) {
    unsigned int u = __builtin_bit_cast(unsigned int, f);
    u += 0x7fffu + ((u >> 16) & 1u);
    return (unsigned short)(u >> 16);
}
__device__ __forceinline__ float bf16_to_f(unsigned short h) {
    return __builtin_bit_cast(float, (unsigned int)h << 16);
}
__device__ __forceinline__ float exp2_hw(float x) {
    float r;
    asm("v_exp_f32 %0, %1" : "=v"(r) : "v"(x));
    return r;
}
__device__ __forceinline__ unsigned int cvtpk_bf16(float lo, float hi) {
    unsigned int r;
    asm("v_cvt_pk_bf16_f32 %0, %1, %2" : "=v"(r) : "v"(lo), "v"(hi));
    return r;
}

// ---------------------------------------------------------------------------
// convert_v: one-time transpose of wv into wvT[c_in][c_out] with BN scale
// folded. 256KB; writes coalesced. Grid 256 x 256.
// ---------------------------------------------------------------------------
__global__ __launch_bounds__(256) void convert_v(
    const float* __restrict__ wv, const float* __restrict__ vg,
    const float* __restrict__ vv, float* __restrict__ wvt)
{
    const int idx = blockIdx.x * 256 + threadIdx.x;
    const int ci = idx >> 8, o = idx & 255;
    const float sc = vg[o] / sqrtf(vv[o] + 1e-5f);
    wvt[ci * NC + o] = wv[o * NC + ci] * sc;
}

// ---------------------------------------------------------------------------
// Projection kernel v3: 3-way job-split grid for 2x wave occupancy.
// Grid 1536 x 256: job 0 = q/k (blocks 0-511), job 1 = v ch 0-127,
// job 2 = v ch 128-255. Each block stages the same 256x32 x-tile (x re-read
// 3x, L3-absorbed; HBM at 3% peak). q/k: R2 mapping, hi/lo bf16 split,
// q scaled by log2(e). v: transposed weights wvT (coalesced), direct u16x8
// stores into V'[B][jg][c][8] (PV-fragment order), no LDS transpose.
// ---------------------------------------------------------------------------
__global__ __launch_bounds__(256) void proj_kernel(
    const float* __restrict__ x,
    const float* __restrict__ wq,
    const float* __restrict__ qg, const float* __restrict__ qb,
    const float* __restrict__ qm, const float* __restrict__ qv,
    const float* __restrict__ wk,
    const float* __restrict__ kg, const float* __restrict__ kb,
    const float* __restrict__ km, const float* __restrict__ kv,
    const float* __restrict__ wvt,
    const float* __restrict__ vg, const float* __restrict__ vb,
    const float* __restrict__ vm, const float* __restrict__ vv,
    unsigned short* __restrict__ qhi, unsigned short* __restrict__ qlo,
    unsigned short* __restrict__ khi, unsigned short* __restrict__ klo,
    unsigned short* __restrict__ vws)
{
    __shared__ float xt[NC * 36 + 8];
    const int t = threadIdx.x;
    const int blk = blockIdx.x;
    const int job = blk >> 9;               // 0 = q/k, 1 = v-low, 2 = v-high
    const int tile = blk & 511;
    const int b = tile >> 7;
    const int n0 = (tile & 127) << 5;
    const float* xb = x + ((size_t)b << 20);

    for (int idx = t; idx < NC * 32; idx += 256) {
        int c = idx >> 5, j = idx & 31;
        xt[c * 36 + j] = xb[((size_t)c << 12) + n0 + j];
    }
    __syncthreads();

    if (job == 0) {
        // ---- q / k (R2 mapping): thread = (p = t&31, og = t>>5) ----
        const int p = t & 31;
        const int og = t >> 5;
        const bool is_k = og >= 4;
        const int o0 = (og & 3) << 3;
        const float* w = is_k ? wk : wq;
        float acc[8];
#pragma unroll
        for (int o = 0; o < 8; ++o) acc[o] = 0.f;
        for (int c4 = 0; c4 < NC; c4 += 4) {
            float x0 = xt[(c4 + 0) * 36 + p];
            float x1 = xt[(c4 + 1) * 36 + p];
            float x2 = xt[(c4 + 2) * 36 + p];
            float x3 = xt[(c4 + 3) * 36 + p];
#pragma unroll
            for (int o = 0; o < 8; ++o) {
                const float4 w4 = *(const float4*)&w[(o0 + o) * NC + c4];
                acc[o] += w4.x * x0 + w4.y * x1 + w4.z * x2 + w4.w * x3;
            }
        }
        const float* G = is_k ? kg : qg;
        const float* Bb = is_k ? kb : qb;
        const float* M = is_k ? km : qm;
        const float* V = is_k ? kv : qv;
        u16x8 hv, lv;
#pragma unroll
        for (int o = 0; o < 8; ++o) {
            int oo = o0 + o;
            float sc = G[oo] / sqrtf(V[oo] + 1e-5f);
            float val = acc[o] * sc + (Bb[oo] - M[oo] * sc);
            if (!is_k) val *= LOG2E;
            unsigned short h = bf16_rne(val);
            hv[o] = h;
            lv[o] = bf16_rne(val - bf16_to_f(h));
        }
        size_t base = ((size_t)(b << 12) + n0 + p) * 32 + o0;
        *(u16x8*)&(is_k ? khi : qhi)[base] = hv;
        *(u16x8*)&(is_k ? klo : qlo)[base] = lv;
    } else {
        // ---- v : thread = (cg = t&63, pg = t>>6); 2 channels x 8 pos ----
        const int vh = job - 1;             // channel base vh*128
        const int cg = t & 63;
        const int pg = t >> 6;
        const int p0 = pg << 3;
        float acc[8][2];
#pragma unroll
        for (int pp = 0; pp < 8; ++pp) {
            acc[pp][0] = 0.f;
            acc[pp][1] = 0.f;
        }
        for (int c4 = 0; c4 < NC; c4 += 4) {
#pragma unroll
            for (int r = 0; r < 4; ++r) {
                const int ci = c4 + r;
                const float w0 = wvt[ci * NC + vh * 128 + cg];
                const float w1 = wvt[ci * NC + vh * 128 + cg + 64];
                const float4 xa = *(const float4*)&xt[ci * 36 + p0];
                const float4 xc = *(const float4*)&xt[ci * 36 + p0 + 4];
                const float xs[8] = {xa.x, xa.y, xa.z, xa.w,
                                     xc.x, xc.y, xc.z, xc.w};
#pragma unroll
                for (int pp = 0; pp < 8; ++pp) {
                    acc[pp][0] += w0 * xs[pp];
                    acc[pp][1] += w1 * xs[pp];
                }
            }
        }
        const size_t vrow = (size_t)b * (NN / 8) + (n0 >> 3) + pg;
#pragma unroll
        for (int o = 0; o < 2; ++o) {
            const int c = vh * 128 + cg + (o << 6);
            const float sc = vg[c] / sqrtf(vv[c] + 1e-5f);
            const float sh = vb[c] - vm[c] * sc;   // scale already in wvt
            u16x8 st;
#pragma unroll
            for (int pp = 0; pp < 8; ++pp) st[pp] = bf16_rne(acc[pp][o] + sh);
            *(u16x8*)&vws[(vrow * NC + c) * 8] = st;
        }
    }
}

// ---------------------------------------------------------------------------
// Flash attention v12 = R14 + V double-buffered one jt ahead (K already was).
// All 12 loads for jt+1 issue at body top of jt -> ~1500 cyc in flight before
// use; compiler emits counted vmcnt (only older loads drained). VGPR +32 —
// free, occupancy is grid-capped at 2 blocks/CU. Main loop: zero LDS /
// zero barriers, K,V direct-from-global (L2-hot).
// ---------------------------------------------------------------------------
__global__ __launch_bounds__(256, 2) void attn_kernel(
    const float* __restrict__ x, const float* __restrict__ gamma_p,
    const unsigned short* __restrict__ qhi, const unsigned short* __restrict__ qlo,
    const unsigned short* __restrict__ khi, const unsigned short* __restrict__ klo,
    const unsigned short* __restrict__ vws,
    float* __restrict__ out)
{
    __shared__ __align__(16) char smem[33792];
    const int t = threadIdx.x;
    const int pb = blockIdx.x;
    const int xcd = pb & 7;
    const int b = xcd >> 1;
    const int tile = ((xcd & 1) << 6) + (pb >> 3);
    const int i0 = tile << 5;
    const int w = t >> 6, lane = t & 63;
    const int h = lane >> 5, il = lane & 31;
    const int wc = w & 1, wjp = w >> 1;

    const size_t bN32 = (size_t)b * (NN * 32);
    const unsigned short* kh_g = khi + bN32;
    const unsigned short* kl_g = klo + bN32;
    const unsigned short* v_g = vws + (size_t)b * (NC * NN);

    // Q B-frags: lane holds Q[i = i0+il][c = ks*16 + h*8 + e], hi/lo
    bf16x8 qh[2], ql[2];
    {
        size_t qoff = bN32 + (size_t)(i0 + il) * 32 + h * 8;
        qh[0] = *(const bf16x8*)&qhi[qoff];
        ql[0] = *(const bf16x8*)&qlo[qoff];
        qh[1] = *(const bf16x8*)&qhi[qoff + 16];
        ql[1] = *(const bf16x8*)&qlo[qoff + 16];
    }

    // K A-frag row: S^T row (wjp*32+il) <-> global row kmap(il) (swap bits 2<->3)
    size_t krow;
    {
        int u = il;
        int kmp = (u & 0x13) | ((u & 4) << 1) | ((u & 8) >> 1);
        krow = ((size_t)(wjp * 32 + kmp) * 32) + h * 8;   // + j0*32 per jt
    }

    f32x16 acc[4];
#pragma unroll
    for (int fc = 0; fc < 4; ++fc)
#pragma unroll
        for (int e = 0; e < 16; ++e) acc[fc][e] = 0.f;
    float m_run = -3.0e38f, l_part = 0.f;   // per lane: q-row i = il

    auto kfetch = [&](int jt, bf16x8* kr) {
        const size_t rb = krow + (size_t)(jt << 6) * 32;
        kr[0] = *(const bf16x8*)&kh_g[rb];
        kr[1] = *(const bf16x8*)&kh_g[rb + 16];
        kr[2] = *(const bf16x8*)&kl_g[rb];
        kr[3] = *(const bf16x8*)&kl_g[rb + 16];
    };
    auto vfetch = [&](int jt, bf16x8* vr) {
#pragma unroll
        for (int fc = 0; fc < 4; ++fc)
#pragma unroll
            for (int ks = 0; ks < 2; ++ks) {
                const int c = wc * 128 + fc * 32 + il;
                const size_t jg = (size_t)(jt * 8 + wjp * 4 + ks * 2 + h);
                vr[fc * 2 + ks] = *(const bf16x8*)&v_g[(jg * NC + c) * 8];
            }
    };

    bf16x8 kreg[2][4];
    bf16x8 vreg[2][8];
    kfetch(0, kreg[0]);
    vfetch(0, vreg[0]);

#pragma unroll 2
    for (int jt = 0; jt < NN / 64; ++jt) {
        const int cb = jt & 1;
        if (jt < NN / 64 - 1) {
            kfetch(jt + 1, kreg[cb ^ 1]);
            vfetch(jt + 1, vreg[cb ^ 1]);
        }

        // ---- S^T = K·Q (32x32, hi/lo, log2 domain): D[j-row][i = il] ----
        f32x16 s2;
#pragma unroll
        for (int e = 0; e < 16; ++e) s2[e] = 0.f;
        __builtin_amdgcn_s_setprio(1);
#pragma unroll
        for (int ks = 0; ks < 2; ++ks) {
            s2 = MFMA32(kreg[cb][2 + ks], qh[ks], s2);
            s2 = MFMA32(kreg[cb][ks], ql[ks], s2);
            s2 = MFMA32(kreg[cb][ks], qh[ks], s2);
        }
        __builtin_amdgcn_s_setprio(0);

        // ---- online softmax (row i = il; halves combined via xor-32) ----
        float tl = s2[0];
#pragma unroll
        for (int e = 1; e < 16; ++e) tl = fmaxf(tl, s2[e]);
        tl = fmaxf(tl, __shfl_xor(tl, 32));

        if (!__all(tl <= m_run + 11.0f)) {
            float nm = fmaxf(m_run, tl);
            float rs = exp2_hw(m_run - nm);
            m_run = nm;
            l_part *= rs;
#pragma unroll
            for (int fc = 0; fc < 4; ++fc)
#pragma unroll
                for (int e = 0; e < 16; ++e) acc[fc][e] *= rs;
        }

        float p[16];
#pragma unroll
        for (int e = 0; e < 16; ++e) p[e] = exp2_hw(s2[e] - m_run);
        float ls = 0.f;
#pragma unroll
        for (int e = 0; e < 16; ++e) ls += p[e];
        ls += __shfl_xor(ls, 32);
        l_part += ls;

        // ---- P -> bf16 B-frags (j-order correct via kmap) ----
        bf16x8 pa[2];
#pragma unroll
        for (int ks = 0; ks < 2; ++ks) {
            u32x4 pw;
            pw[0] = cvtpk_bf16(p[ks * 8 + 0], p[ks * 8 + 1]);
            pw[1] = cvtpk_bf16(p[ks * 8 + 2], p[ks * 8 + 3]);
            pw[2] = cvtpk_bf16(p[ks * 8 + 4], p[ks * 8 + 5]);
            pw[3] = cvtpk_bf16(p[ks * 8 + 6], p[ks * 8 + 7]);
            pa[ks] = __builtin_bit_cast(bf16x8, pw);
        }

        // ---- PV: acc[fc] = V[c][j] (A) x P[j][i] (B), D[c-row][i-col] ----
        __builtin_amdgcn_s_setprio(1);
#pragma unroll
        for (int fc = 0; fc < 4; ++fc) {
#pragma unroll
            for (int ks = 0; ks < 2; ++ks)
                acc[fc] = MFMA32(vreg[cb][fc * 2 + ks], pa[ks], acc[fc]);
        }
        __builtin_amdgcn_s_setprio(0);
    }

    // ---- merge wjp partials (in-place buffer), normalize, residual, store ----
    float* ml = (float*)(smem + 32768);       // m: [w*32+i], l: [128 + w*32+i]
    if (lane < 32) {
        ml[w * 32 + il] = m_run;
        ml[128 + w * 32 + il] = l_part;
    }
    __syncthreads();

    const int wp = w ^ 2;                     // partner wave (wjp flipped)
    float m_o = ml[wp * 32 + il];
    float l_o = ml[128 + wp * 32 + il];
    float m_g = fmaxf(m_run, m_o);
    float a_s = exp2_hw(m_run - m_g);
    float l_tot = l_part * a_s + l_o * exp2_hw(m_o - m_g);
#pragma unroll
    for (int fc = 0; fc < 4; ++fc)
#pragma unroll
        for (int e = 0; e < 16; ++e) acc[fc][e] *= a_s;

    float* AB = (float*)smem;                 // [256 c][32 i], in-place
    if (wjp == 1) {
#pragma unroll
        for (int fc = 0; fc < 4; ++fc)
#pragma unroll
            for (int e = 0; e < 16; ++e) {
                int c = wc * 128 + fc * 32 + (e & 3) + 8 * (e >> 2) + 4 * h;
                AB[c * 32 + il] = acc[fc][e];
            }
    }
    __syncthreads();

    if (wjp == 0) {
        const float gm = gamma_p[0];
        const float linv = gm / l_tot;
#pragma unroll
        for (int fc = 0; fc < 4; ++fc)
#pragma unroll
            for (int e = 0; e < 16; ++e) {
                int c = wc * 128 + fc * 32 + (e & 3) + 8 * (e >> 2) + 4 * h;
                AB[c * 32 + il] = (acc[fc][e] + AB[c * 32 + il]) * linv;
            }
    }
    __syncthreads();

    const float* xb = x + ((size_t)b << 20);
    float* ob = out + ((size_t)b << 20);
#pragma unroll
    for (int it = 0; it < 8; ++it) {
        int c = (t >> 3) + (it << 5);
        int j = t & 7;
        f32x4 v = *(const f32x4*)&AB[c * 32 + j * 4];
        f32x4 xv = *(const f32x4*)&xb[((size_t)c << 12) + i0 + j * 4];
        v += xv;
        *(f32x4*)&ob[((size_t)c << 12) + i0 + j * 4] = v;
    }
}

// ---------------------------------------------------------------------------
extern "C" void kernel_launch(void* const* d_in, const int* in_sizes, int n_in,
                              void* d_out, int out_size, void* d_ws, size_t ws_size,
                              hipStream_t stream)
{
    (void)in_sizes; (void)n_in; (void)out_size; (void)ws_size;
    const float* x = (const float*)d_in[0];
    const float* wq = (const float*)d_in[1];
    const float* qg = (const float*)d_in[2];
    const float* qb = (const float*)d_in[3];
    const float* qm = (const float*)d_in[4];
    const float* qv = (const float*)d_in[5];
    const float* wk = (const float*)d_in[6];
    const float* kg = (const float*)d_in[7];
    const float* kb = (const float*)d_in[8];
    const float* km = (const float*)d_in[9];
    const float* kv = (const float*)d_in[10];
    const float* wv = (const float*)d_in[11];
    const float* vg = (const float*)d_in[12];
    const float* vb = (const float*)d_in[13];
    const float* vm = (const float*)d_in[14];
    const float* vv = (const float*)d_in[15];
    const float* gamma = (const float*)d_in[16];

    unsigned short* ws = (unsigned short*)d_ws;
    const size_t QK = (size_t)NB * NN * 32;       // 524288 ushorts
    const size_t VSZ = (size_t)NB * NC * NN;      // 4194304 ushorts
    unsigned short* qhi = ws;
    unsigned short* qlo = ws + QK;
    unsigned short* khi = ws + 2 * QK;
    unsigned short* klo = ws + 3 * QK;
    unsigned short* vws = ws + 4 * QK;
    float* wvt = (float*)(ws + 4 * QK + VSZ);     // 65536 floats (256KB)

    convert_v<<<dim3(256), dim3(256), 0, stream>>>(wv, vg, vv, wvt);
    proj_kernel<<<dim3(1536), dim3(256), 0, stream>>>(
        x, wq, qg, qb, qm, qv, wk, kg, kb, km, kv, wvt, vg, vb, vm, vv,
        qhi, qlo, khi, klo, vws);
    attn_kernel<<<dim3(512), dim3(256), 0, stream>>>(
        x, gamma, qhi, qlo, khi, klo, vws, (float*)d_out);
}